// Round 6
// baseline (421.811 us; speedup 1.0000x reference)
//
#include <hip/hip_runtime.h>
#include <math.h>

// ---------------------------------------------------------------------------
// GAT pipeline (R6):
//   wsplit + CSR build (count -> 3-phase scan -> scatter)  [once per launch]
//   per layer: split-bf16 MFMA GEMM (fused attn stats, bf16 xl out)
//              -> online-softmax agg (H=4: 2 waves/node, 4ch/lane, 8-batch)
//   mean pool -> 2-layer MLP -> scalar out
// R5 post-mortem: 8-batch s16x8 cost 32 VGPRs -> occupancy 48->34%, agg
//   regressed 55->59us. Serial chain per wave is the limiter, not ILP.
// R6: split node channels across 2 waves (s16x4 batch = half the VGPRs,
//   2x wave parallelism, half serial work/wave).
// ---------------------------------------------------------------------------

typedef float f32x4 __attribute__((ext_vector_type(4)));
typedef short s16x8 __attribute__((ext_vector_type(8)));
typedef short s16x4 __attribute__((ext_vector_type(4)));

__device__ inline ushort f2bf(float f) {
  unsigned u = __float_as_uint(f);
  u += 0x7FFF + ((u >> 16) & 1);          // round-to-nearest-even
  return (ushort)(u >> 16);
}
__device__ inline float bf2f(ushort h) { return __uint_as_float((unsigned)h << 16); }

// ---------------- CSR build ----------------
__global__ void count_kernel(const int* __restrict__ ei, int* __restrict__ counts,
                             int E, int n) {
  int t = blockIdx.x * blockDim.x + threadIdx.x;
  if (t < E) {
    atomicAdd(&counts[ei[E + t]], 1);          // dst row of edge_index
  } else if (t < E + n) {
    atomicAdd(&counts[t - E], 1);              // self loop
  }
}

// phase 1: per-block (256) sums
__global__ void scan1_kernel(const int* __restrict__ counts, int* __restrict__ partials,
                             int n) {
  __shared__ int sd[4];
  int i = blockIdx.x * 256 + threadIdx.x;
  int v = (i < n) ? counts[i] : 0;
  for (int m = 32; m; m >>= 1) v += __shfl_xor(v, m);
  if ((threadIdx.x & 63) == 0) sd[threadIdx.x >> 6] = v;
  __syncthreads();
  if (threadIdx.x == 0) partials[blockIdx.x] = sd[0] + sd[1] + sd[2] + sd[3];
}

// phase 2: exclusive scan of partials (nb <= 1024), single small block
__global__ void scan2_kernel(int* __restrict__ partials, int nb) {
  __shared__ int sd[1024];
  int t = threadIdx.x;
  int v = (t < nb) ? partials[t] : 0;
  sd[t] = v;
  __syncthreads();
  for (int off = 1; off < 1024; off <<= 1) {
    int u = (t >= off) ? sd[t - off] : 0;
    __syncthreads();
    sd[t] += u;
    __syncthreads();
  }
  if (t < nb) partials[t] = sd[t] - v;
}

// phase 3: per-block exclusive scan + carry
__global__ void scan3_kernel(const int* __restrict__ counts, const int* __restrict__ partials,
                             int* __restrict__ offsets, int n) {
  __shared__ int sd[256];
  int i = blockIdx.x * 256 + threadIdx.x;
  int t = threadIdx.x;
  int v = (i < n) ? counts[i] : 0;
  sd[t] = v;
  __syncthreads();
  for (int off = 1; off < 256; off <<= 1) {
    int u = (t >= off) ? sd[t - off] : 0;
    __syncthreads();
    sd[t] += u;
    __syncthreads();
  }
  int carry = partials[blockIdx.x];
  if (i < n) {
    offsets[i] = carry + sd[t] - v;
    if (i == n - 1) offsets[n] = carry + sd[t];
  }
}

__global__ void scatter_kernel(const int* __restrict__ ei, const int* __restrict__ offsets,
                               int* __restrict__ cursor, int* __restrict__ srcs,
                               int E, int n) {
  int t = blockIdx.x * blockDim.x + threadIdx.x;
  int s, d;
  if (t < E)          { s = ei[t]; d = ei[E + t]; }
  else if (t < E + n) { s = t - E; d = s; }
  else return;
  int pos = offsets[d] + atomicAdd(&cursor[d], 1);
  srcs[pos] = s;
}

// ------- weight transpose + bf16 split for all 3 layers in one launch -------
__global__ void wsplit_all_kernel(
    const float* __restrict__ W0, const float* __restrict__ W1,
    const float* __restrict__ W2, ushort* __restrict__ w0h, ushort* __restrict__ w0l,
    ushort* __restrict__ w1h, ushort* __restrict__ w1l, ushort* __restrict__ w2h,
    ushort* __restrict__ w2l) {
  int idx = blockIdx.x * 256 + threadIdx.x;
  const float* W; ushort *th, *tl; int K, N;
  if (idx < 16384)      { W = W0; th = w0h; tl = w0l; K = 128; N = 512; }
  else if (idx < 81920) { idx -= 16384; W = W1; th = w1h; tl = w1l; K = 512; N = 512; }
  else if (idx < 98304) { idx -= 81920; W = W2; th = w2h; tl = w2l; K = 512; N = 128; }
  else return;
  int n = idx % N;
  int k4 = (idx / N) << 2;
  s16x4 hv, lv;
#pragma unroll
  for (int r = 0; r < 4; ++r) {
    float w = W[(size_t)(k4 + r) * N + n];
    ushort h = f2bf(w);
    hv[r] = (short)h;
    lv[r] = (short)f2bf(w - bf2f(h));
  }
  *(s16x4*)&th[(size_t)n * K + k4] = hv;
  *(s16x4*)&tl[(size_t)n * K + k4] = lv;
}

// ---------------- split-bf16 MFMA GEMM + fused per-head attn stats ----------
// Cb[M,N] (bf16) = A[M,K] @ B[K,N]; block col range = one head (128 cols).
// asn/adn[M,H] = per-row dot of fp32 accum with a_s/a_d[h,0:128] (exact).
// BM=64, BN=128, BK=32; 256 threads = 4 waves (2x2), 16x16x32 MFMA.
__global__ __launch_bounds__(256, 2) void gemm_mfma_kernel(
    const float* __restrict__ A, const ushort* __restrict__ Bth,
    const ushort* __restrict__ Btl, ushort* __restrict__ Cb,
    const float* __restrict__ a_s, const float* __restrict__ a_d,
    float* __restrict__ asn, float* __restrict__ adn,
    int M, int K, int N, int H) {
  __shared__ ushort Ash[64][40], Asl[64][40];
  __shared__ ushort Bsh[128][40], Bsl[128][40];
  __shared__ float st_sh[2][64][2];           // [src/dst][row][wave-col-half]
  int tid = threadIdx.x;
  int row0 = blockIdx.y * 64, col0 = blockIdx.x * 128;
  int hidx = blockIdx.x;                      // head index (N==H*128)
  int am = tid >> 2, ak = (tid & 3) << 3;     // A stage: row am, 8 k-vals
  int bn = tid >> 1, bk = (tid & 1) << 4;     // B stage: row bn, 16 k-vals
  int lane = tid & 63, wid = tid >> 6;
  int wm = (wid & 1) << 5, wn = (wid >> 1) << 6;
  int fr = lane & 15, fq = (lane >> 4) << 3;  // fragment row/col, k-offset
  f32x4 acc[2][4] = {};
  const float* Arow = A + (size_t)(row0 + am) * K;
  bool avalid = (row0 + am) < M;
  const ushort* bhp = Bth + (size_t)(col0 + bn) * K + bk;
  const ushort* blp = Btl + (size_t)(col0 + bn) * K + bk;

  for (int k0 = 0; k0 < K; k0 += 32) {
    // ---- stage A (fp32 -> hi/lo bf16) ----
    float v[8];
    if (avalid) {
      float4 t0 = *(const float4*)(Arow + k0 + ak);
      float4 t1 = *(const float4*)(Arow + k0 + ak + 4);
      v[0] = t0.x; v[1] = t0.y; v[2] = t0.z; v[3] = t0.w;
      v[4] = t1.x; v[5] = t1.y; v[6] = t1.z; v[7] = t1.w;
    } else {
#pragma unroll
      for (int r = 0; r < 8; ++r) v[r] = 0.f;
    }
    s16x8 hv, lv;
#pragma unroll
    for (int r = 0; r < 8; ++r) {
      ushort h = f2bf(v[r]);
      hv[r] = (short)h;
      lv[r] = (short)f2bf(v[r] - bf2f(h));
    }
    *(s16x8*)&Ash[am][ak] = hv;
    *(s16x8*)&Asl[am][ak] = lv;
    // ---- stage B (pre-split ushort copy) ----
    *(s16x8*)&Bsh[bn][bk]     = *(const s16x8*)(bhp + k0);
    *(s16x8*)&Bsh[bn][bk + 8] = *(const s16x8*)(bhp + k0 + 8);
    *(s16x8*)&Bsl[bn][bk]     = *(const s16x8*)(blp + k0);
    *(s16x8*)&Bsl[bn][bk + 8] = *(const s16x8*)(blp + k0 + 8);
    __syncthreads();
    // ---- fragments + MFMA (ah*bh + ah*bl + al*bh) ----
    s16x8 ah[2], al[2], bh[4], bl[4];
#pragma unroll
    for (int i = 0; i < 2; ++i) {
      ah[i] = *(const s16x8*)&Ash[wm + i * 16 + fr][fq];
      al[i] = *(const s16x8*)&Asl[wm + i * 16 + fr][fq];
    }
#pragma unroll
    for (int j = 0; j < 4; ++j) {
      bh[j] = *(const s16x8*)&Bsh[wn + j * 16 + fr][fq];
      bl[j] = *(const s16x8*)&Bsl[wn + j * 16 + fr][fq];
    }
#pragma unroll
    for (int i = 0; i < 2; ++i)
#pragma unroll
      for (int j = 0; j < 4; ++j) {
        acc[i][j] = __builtin_amdgcn_mfma_f32_16x16x32_bf16(ah[i], bh[j], acc[i][j], 0, 0, 0);
        acc[i][j] = __builtin_amdgcn_mfma_f32_16x16x32_bf16(ah[i], bl[j], acc[i][j], 0, 0, 0);
        acc[i][j] = __builtin_amdgcn_mfma_f32_16x16x32_bf16(al[i], bh[j], acc[i][j], 0, 0, 0);
      }
    __syncthreads();
  }
  // ---- epilogue: bf16 store + fused stats ----
  // C/D layout: col = lane&15 (fr), row = (lane>>4)*4 + reg
  float asv[4], adv[4];
#pragma unroll
  for (int j = 0; j < 4; ++j) {
    asv[j] = a_s[hidx * 128 + wn + j * 16 + fr];
    adv[j] = a_d[hidx * 128 + wn + j * 16 + fr];
  }
  int rb = row0 + wm + ((lane >> 4) << 2);
  int cb = col0 + wn + fr;
#pragma unroll
  for (int i = 0; i < 2; ++i)
#pragma unroll
    for (int r = 0; r < 4; ++r) {
      int row = rb + i * 16 + r;
      float sp = 0.f, dp = 0.f;
#pragma unroll
      for (int j = 0; j < 4; ++j) {
        float c = acc[i][j][r];
        sp += c * asv[j];
        dp += c * adv[j];
        if (row < M) Cb[(size_t)row * N + cb + j * 16] = f2bf(c);
      }
      // reduce over fr (16 lanes per row-group)
#pragma unroll
      for (int m = 1; m < 16; m <<= 1) {
        sp += __shfl_xor(sp, m);
        dp += __shfl_xor(dp, m);
      }
      if ((lane & 15) == 0) {
        int rowb = wm + i * 16 + ((lane >> 4) << 2) + r;
        st_sh[0][rowb][wid >> 1] = sp;
        st_sh[1][rowb][wid >> 1] = dp;
      }
    }
  __syncthreads();
  if (tid < 64) {
    int row = row0 + tid;
    if (row < M) {
      asn[(size_t)row * H + hidx] = st_sh[0][tid][0] + st_sh[0][tid][1];
      adn[(size_t)row * H + hidx] = st_sh[1][tid][0] + st_sh[1][tid][1];
    }
  }
}

// ------- H=4 agg: 2 waves per node (2 heads / 256 ch / 4 ch per lane) -------
__global__ __launch_bounds__(256) void agg4_kernel(
    const ushort* __restrict__ xl, const float* __restrict__ asn,
    const float* __restrict__ adn, const int* __restrict__ offsets,
    const int* __restrict__ srcs, const float* __restrict__ bias,
    float* __restrict__ out, int n) {
  constexpr int HC = 512;
  __shared__ float alpha_sh[4][128];
  __shared__ int src_sh[4][64];
  int wib = threadIdx.x >> 6;
  int lane = threadIdx.x & 63;
  int nd = blockIdx.x * 2 + (wib >> 1);
  if (nd >= n) return;
  int hh = (wib & 1) << 1;             // this wave's head base: 0 or 2
  int beg = offsets[nd];
  int deg = offsets[nd + 1] - beg;
  float2 adl = *(const float2*)&adn[(size_t)nd * 4 + hh];

  // online (m,l) for my 2 heads
  float mh[2], lh[2];
  mh[0] = mh[1] = -3.0e38f; lh[0] = lh[1] = 0.f;
  for (int j0 = 0; j0 < deg; j0 += 64) {
    int j = j0 + lane;
    if (j < deg) {
      int s = srcs[beg + j];
      float2 av = *(const float2*)&asn[(size_t)s * 4 + hh];
      float e0 = av.x + adl.x; e0 = (e0 > 0.f) ? e0 : 0.2f * e0;
      float e1 = av.y + adl.y; e1 = (e1 > 0.f) ? e1 : 0.2f * e1;
      float mn = fmaxf(mh[0], e0);
      lh[0] = lh[0] * __expf(mh[0] - mn) + __expf(e0 - mn); mh[0] = mn;
      mn = fmaxf(mh[1], e1);
      lh[1] = lh[1] * __expf(mh[1] - mn) + __expf(e1 - mn); mh[1] = mn;
    }
  }
#pragma unroll
  for (int h = 0; h < 2; ++h) {
    for (int m = 1; m < 64; m <<= 1) {
      float mo = __shfl_xor(mh[h], m);
      float lo = __shfl_xor(lh[h], m);
      float mn = fmaxf(mh[h], mo);
      lh[h] = lh[h] * __expf(mh[h] - mn) + lo * __expf(mo - mn);
      mh[h] = mn;
    }
    lh[h] = 1.f / lh[h];               // 1/den
  }

  // gather: 4 ch/lane, batch 8 edges (s16x4 loads = 2 VGPRs each)
  float acc[4] = {};
  int ch0 = (hh << 7) + (lane << 2);   // hh*128 + lane*4
  int hl = lane >> 5;                  // 0: head hh, 1: head hh+1
  for (int j0 = 0; j0 < deg; j0 += 64) {
    int j = j0 + lane;
    if (j < deg) {
      int s = srcs[beg + j];
      src_sh[wib][lane] = s;
      float2 av = *(const float2*)&asn[(size_t)s * 4 + hh];
      float e0 = av.x + adl.x; e0 = (e0 > 0.f) ? e0 : 0.2f * e0;
      float e1 = av.y + adl.y; e1 = (e1 > 0.f) ? e1 : 0.2f * e1;
      alpha_sh[wib][lane * 2 + 0] = __expf(e0 - mh[0]) * lh[0];
      alpha_sh[wib][lane * 2 + 1] = __expf(e1 - mh[1]) * lh[1];
    }
    __builtin_amdgcn_wave_barrier();   // wave-lockstep LDS producer->consumer
    int cl = min(64, deg - j0);
    int jj = 0;
    for (; jj + 8 <= cl; jj += 8) {
      s16x4 v[8]; float a[8];
#pragma unroll
      for (int u = 0; u < 8; ++u) {
        int s = src_sh[wib][jj + u];
        a[u] = alpha_sh[wib][(jj + u) * 2 + hl];
        v[u] = *(const s16x4*)(xl + (size_t)s * HC + ch0);
      }
#pragma unroll
      for (int u = 0; u < 8; ++u) {
        acc[0] += a[u] * bf2f((ushort)v[u][0]);
        acc[1] += a[u] * bf2f((ushort)v[u][1]);
        acc[2] += a[u] * bf2f((ushort)v[u][2]);
        acc[3] += a[u] * bf2f((ushort)v[u][3]);
      }
    }
    for (; jj < cl; ++jj) {
      int s = src_sh[wib][jj];
      float a = alpha_sh[wib][jj * 2 + hl];
      s16x4 v = *(const s16x4*)(xl + (size_t)s * HC + ch0);
      acc[0] += a * bf2f((ushort)v[0]);
      acc[1] += a * bf2f((ushort)v[1]);
      acc[2] += a * bf2f((ushort)v[2]);
      acc[3] += a * bf2f((ushort)v[3]);
    }
    __builtin_amdgcn_wave_barrier();
  }
  float* op = out + (size_t)nd * HC + ch0;
#pragma unroll
  for (int i = 0; i < 4; ++i) op[i] = fmaxf(acc[i] + bias[ch0 + i], 0.f);
}

// ------- H=1 agg (layer 2): wave per node, 2 ch/lane -------
__global__ __launch_bounds__(256) void agg1_kernel(
    const ushort* __restrict__ xl, const float* __restrict__ asn,
    const float* __restrict__ adn, const int* __restrict__ offsets,
    const int* __restrict__ srcs, const float* __restrict__ bias,
    float* __restrict__ out, int n) {
  constexpr int HC = 128;
  __shared__ float alpha_sh[4][64];
  __shared__ int src_sh[4][64];
  int wib = threadIdx.x >> 6;
  int lane = threadIdx.x & 63;
  int nd = blockIdx.x * 4 + wib;
  if (nd >= n) return;
  int beg = offsets[nd];
  int deg = offsets[nd + 1] - beg;
  float adl = adn[nd];

  float mh = -3.0e38f, lh = 0.f;
  for (int j0 = 0; j0 < deg; j0 += 64) {
    int j = j0 + lane;
    if (j < deg) {
      int s = srcs[beg + j];
      float e = asn[s] + adl;
      e = (e > 0.f) ? e : 0.2f * e;
      float mn = fmaxf(mh, e);
      lh = lh * __expf(mh - mn) + __expf(e - mn);
      mh = mn;
    }
  }
  for (int m = 1; m < 64; m <<= 1) {
    float mo = __shfl_xor(mh, m);
    float lo = __shfl_xor(lh, m);
    float mn = fmaxf(mh, mo);
    lh = lh * __expf(mh - mn) + lo * __expf(mo - mn);
    mh = mn;
  }
  lh = 1.f / lh;

  float acc[2] = {};
  int ch0 = lane * 2;
  for (int j0 = 0; j0 < deg; j0 += 64) {
    int j = j0 + lane;
    if (j < deg) {
      int s = srcs[beg + j];
      src_sh[wib][lane] = s;
      float e = asn[s] + adl;
      e = (e > 0.f) ? e : 0.2f * e;
      alpha_sh[wib][lane] = __expf(e - mh) * lh;
    }
    __builtin_amdgcn_wave_barrier();
    int cl = min(64, deg - j0);
    int jj = 0;
    for (; jj + 8 <= cl; jj += 8) {
      uint v[8]; float a[8];
#pragma unroll
      for (int u = 0; u < 8; ++u) {
        int s = src_sh[wib][jj + u];
        a[u] = alpha_sh[wib][jj + u];
        v[u] = *(const uint*)(xl + (size_t)s * HC + ch0);
      }
#pragma unroll
      for (int u = 0; u < 8; ++u) {
        acc[0] += a[u] * bf2f((ushort)(v[u] & 0xFFFF));
        acc[1] += a[u] * bf2f((ushort)(v[u] >> 16));
      }
    }
    for (; jj < cl; ++jj) {
      int s = src_sh[wib][jj];
      float a = alpha_sh[wib][jj];
      uint v = *(const uint*)(xl + (size_t)s * HC + ch0);
      acc[0] += a * bf2f((ushort)(v & 0xFFFF));
      acc[1] += a * bf2f((ushort)(v >> 16));
    }
    __builtin_amdgcn_wave_barrier();
  }
  float* op = out + (size_t)nd * HC + ch0;
  op[0] = acc[0] + bias[ch0 + 0];
  op[1] = acc[1] + bias[ch0 + 1];
}

// ---------------- mean pool (partial sums + atomics) ----------------
__global__ void pool_kernel(const float* __restrict__ h, float* __restrict__ g, int n) {
  int c = threadIdx.x;                 // 128 threads
  float acc = 0.f;
  for (int r = blockIdx.x; r < n; r += gridDim.x) acc += h[(size_t)r * 128 + c];
  atomicAdd(&g[c], acc);
}

// ---------------- final MLP: relu(g/N @ Wm1 + bm1) @ Wm2 + bm2 ----------------
__global__ void mlp_kernel(const float* __restrict__ g, const float* __restrict__ Wm1,
                           const float* __restrict__ bm1, const float* __restrict__ Wm2,
                           const float* __restrict__ bm2, float* __restrict__ out,
                           float invn) {
  __shared__ float gs[128];
  __shared__ float hs[64];
  int t = threadIdx.x;                 // 64 threads
  gs[t] = g[t] * invn;
  gs[t + 64] = g[t + 64] * invn;
  __syncthreads();
  float acc = bm1[t];
  for (int c = 0; c < 128; ++c) acc += gs[c] * Wm1[c * 64 + t];
  hs[t] = fmaxf(acc, 0.f);
  __syncthreads();
  if (t == 0) {
    float o = bm2[0];
    for (int j = 0; j < 64; ++j) o += hs[j] * Wm2[j];
    out[0] = o;
  }
}

// ---------------------------------------------------------------------------
extern "C" void kernel_launch(void* const* d_in, const int* in_sizes, int n_in,
                              void* d_out, int out_size, void* d_ws, size_t ws_size,
                              hipStream_t stream) {
  const float* x   = (const float*)d_in[0];
  const int*   ei  = (const int*)d_in[1];
  const float* W0  = (const float*)d_in[2];
  const float* as0 = (const float*)d_in[3];
  const float* ad0 = (const float*)d_in[4];
  const float* b0  = (const float*)d_in[5];
  const float* W1  = (const float*)d_in[6];
  const float* as1 = (const float*)d_in[7];
  const float* ad1 = (const float*)d_in[8];
  const float* b1  = (const float*)d_in[9];
  const float* W2  = (const float*)d_in[10];
  const float* as2 = (const float*)d_in[11];
  const float* ad2 = (const float*)d_in[12];
  const float* b2  = (const float*)d_in[13];
  const float* Wm1 = (const float*)d_in[14];
  const float* bm1 = (const float*)d_in[15];
  const float* Wm2 = (const float*)d_in[16];
  const float* bm2 = (const float*)d_in[17];

  const int N = in_sizes[0] / 128;     // 20000
  const int E = in_sizes[1] / 2;       // 320000
  const int ET = E + N;                // with self loops

  // workspace layout
  float*  Bb  = (float*)d_ws;               // N*512 fp32 (h between layers; h2 dest)
  ushort* xlb = (ushort*)(Bb + (size_t)N * 512);  // N*512 bf16 xl
  float*  asn = (float*)(xlb + (size_t)N * 512);  // N*4
  float*  adn = asn + (size_t)N * 4;        // N*4
  float*  g   = adn + (size_t)N * 4;        // 128 pool accumulator
  int* counts = (int*)(g + 128);            // N
  int* cursor = counts + N;                 // N
  int* offs   = cursor + N;                 // N+1
  int* srcs   = offs + N + 1;               // ET
  int* parts  = srcs + ET;                  // ~128 scan partials
  // transposed+split weights (ushort), 64B-aligned
  ushort* w0h = (ushort*)(((uintptr_t)(parts + 1024) + 63) & ~(uintptr_t)63);
  ushort* w0l = w0h + 512 * 128;
  ushort* w1h = w0l + 512 * 128;
  ushort* w1l = w1h + 512 * 512;
  ushort* w2h = w1l + 512 * 512;
  ushort* w2l = w2h + 128 * 512;

  // zero pool accumulator + counts + cursor (contiguous)
  hipMemsetAsync(g, 0, (size_t)(128 + 2 * N) * sizeof(int), stream);

  // weight transpose + split (one kernel)
  wsplit_all_kernel<<<(98304 + 255) / 256, 256, 0, stream>>>(
      W0, W1, W2, w0h, w0l, w1h, w1l, w2h, w2l);

  // CSR by dst (multi-block scan)
  int ebl = (ET + 255) / 256;
  int nb = (N + 255) / 256;            // 79 scan blocks
  count_kernel<<<ebl, 256, 0, stream>>>(ei, counts, E, N);
  scan1_kernel<<<nb, 256, 0, stream>>>(counts, parts, N);
  scan2_kernel<<<1, 1024, 0, stream>>>(parts, nb);
  scan3_kernel<<<nb, 256, 0, stream>>>(counts, parts, offs, N);
  scatter_kernel<<<ebl, 256, 0, stream>>>(ei, offs, cursor, srcs, E, N);

  int nwb2 = (N + 1) / 2;              // agg4: 2 nodes/block (2 waves/node)
  int nwb4 = (N + 3) / 4;              // agg1: 4 nodes/block
  dim3 gG01(4, (N + 63) / 64);         // N=512: 4 heads x 313 row-blocks
  dim3 gG2(1, (N + 63) / 64);          // N=128: 1 head

  // layer 0: x[N,128] @ W0 -> xlb (bf16) + stats
  gemm_mfma_kernel<<<gG01, 256, 0, stream>>>(x, w0h, w0l, xlb, as0, ad0, asn, adn,
                                             N, 128, 512, 4);
  agg4_kernel<<<nwb2, 256, 0, stream>>>(xlb, asn, adn, offs, srcs, b0, Bb, N);

  // layer 1: h0[N,512] @ W1 -> xlb + stats
  gemm_mfma_kernel<<<gG01, 256, 0, stream>>>(Bb, w1h, w1l, xlb, as1, ad1, asn, adn,
                                             N, 512, 512, 4);
  agg4_kernel<<<nwb2, 256, 0, stream>>>(xlb, asn, adn, offs, srcs, b1, Bb, N);

  // layer 2: h1[N,512] @ W2 -> xlb (N*128) + stats; agg writes h2 into Bb
  gemm_mfma_kernel<<<gG2, 256, 0, stream>>>(Bb, w2h, w2l, xlb, as2, ad2, asn, adn,
                                            N, 512, 128, 1);
  agg1_kernel<<<nwb4, 256, 0, stream>>>(xlb, asn, adn, offs, srcs, b2, Bb, N);

  // mean pool + MLP
  pool_kernel<<<128, 128, 0, stream>>>(Bb, g, N);
  mlp_kernel<<<1, 64, 0, stream>>>(g, Wm1, bm1, Wm2, bm2, (float*)d_out, 1.0f / (float)N);
}